// Round 7
// baseline (337.246 us; speedup 1.0000x reference)
//
#include <hip/hip_runtime.h>
#include <hip/hip_bf16.h>

// SVXSoftmax: cos = norm(input) @ norm(weight)^T ; margin transform ; *32
// B=512, D=512, C=100000.  out[512][100000] f32.
//
// r7: split shape.
//  - prep: gt + bf16-normalized input packed in MFMA fragment order (512KB).
//  - wpack: stream W f32 -> raw bf16 packed in fragment order (98MiB in ws)
//    + per-row invnorm array (applied post-MFMA; r4-proven numerics).
//  - gemmB: NO LDS, NO barriers, no conversion. Pure 1KB-coalesced fragment
//    loads (A dist-2, B dist-4 register rotation, fully unrolled = static
//    indices) + MFMA + fused margin epilogue. Block = 8 waves = 512M x 64N
//    (B read once per block, L3-hot from wpack).
//  - fallback to r6 fused kernel if ws_size too small.

#define S_SCALE 32.0f
#define MARGIN  0.35f
#define T_BOOST 0.2f
#define EPSN    1e-12f

constexpr int Bn = 512;      // batch
constexpr int Dn = 512;      // dim
constexpr int Cn = 100000;   // classes
constexpr int CG = Cn / 16;  // 6250 class groups of 16

typedef __attribute__((ext_vector_type(8))) short bf16x8;
typedef __attribute__((ext_vector_type(4))) float f32x4;

static __device__ inline unsigned short f32_bf16(float f) {
    unsigned int u = __float_as_uint(f);
    u += 0x7FFFu + ((u >> 16) & 1u);     // round-to-nearest-even
    return (unsigned short)(u >> 16);
}

// fragment packing: byte = (g<<14) + (s<<10) + (lane<<4) + (k&7)*2
//   g = row>>4, s = k>>5, lane = ((k>>3)&3)*16 + (row&15)
__global__ __launch_bounds__(256) void prep_kernel(const float* __restrict__ in,
                                                   const float* __restrict__ w,
                                                   const int* __restrict__ label,
                                                   float* __restrict__ gt,
                                                   unsigned short* __restrict__ in_p) {
    int b = blockIdx.x, t = threadIdx.x;
    const float* irow = in + (size_t)b * Dn;
    int lab = label[b];
    const float* wrow = w + (size_t)lab * Dn;
    int c = 2 * t;
    float xa = irow[c], xb = irow[c + 1];
    float ya = wrow[c], yb = wrow[c + 1];
    float s_ii = xa*xa + xb*xb, s_ww = ya*ya + yb*yb, s_iw = xa*ya + xb*yb;
    #pragma unroll
    for (int off = 32; off; off >>= 1) {
        s_ii += __shfl_xor(s_ii, off);
        s_ww += __shfl_xor(s_ww, off);
        s_iw += __shfl_xor(s_iw, off);
    }
    __shared__ float r0[4], r1[4], r2[4], bc[1];
    int wid = t >> 6;
    if ((t & 63) == 0) { r0[wid] = s_ii; r1[wid] = s_ww; r2[wid] = s_iw; }
    __syncthreads();
    if (t == 0) {
        float a  = r0[0] + r0[1] + r0[2] + r0[3];
        float cc = r1[0] + r1[1] + r1[2] + r1[3];
        float d  = r2[0] + r2[1] + r2[2] + r2[3];
        float inv_i = 1.0f / fmaxf(sqrtf(a), EPSN);
        float g = d * inv_i / fmaxf(sqrtf(cc), EPSN);
        gt[b] = fminf(fmaxf(g, -1.0f), 1.0f);
        bc[0] = inv_i;
    }
    __syncthreads();
    float inv_i = bc[0];
    int g = b >> 4, l15 = b & 15;
    int s = t >> 4, lk = (t >> 2) & 3, j2 = (t & 3) * 4;
    int lane = lk * 16 + l15;
    unsigned int off = (unsigned)((g << 14) + (s << 10) + (lane << 4)) + j2;
    unsigned int h0 = f32_bf16(xa * inv_i), h1 = f32_bf16(xb * inv_i);
    *(unsigned int*)((char*)in_p + off) = h0 | (h1 << 16);
}

// ---------------- wpack: W f32 -> raw bf16 fragment-packed + invnorm ----------------
// one wave per 16 classes; lane l: class cg*16+(l&15), k-chunk (l>>4)*8 per s.
__global__ __launch_bounds__(256) void wpack_kernel(const float* __restrict__ w,
                                                    float* __restrict__ winv,
                                                    unsigned short* __restrict__ wp) {
    int wave = blockIdx.x * 4 + (threadIdx.x >> 6);
    int lane = threadIdx.x & 63;
    bool valid = wave < CG;
    int cg = valid ? wave : CG - 1;
    int c  = cg * 16 + (lane & 15);
    int lk = lane >> 4;
    const float* src = w + (size_t)c * Dn + lk * 8;
    char* dst = (char*)wp + ((size_t)cg << 14) + (lane << 4);
    float ss = 0.f;
    #pragma unroll
    for (int s = 0; s < 16; ++s) {
        f32x4 v0 = *(const f32x4*)(src + s * 32);
        f32x4 v1 = *(const f32x4*)(src + s * 32 + 4);
        ss += v0[0]*v0[0] + v0[1]*v0[1] + v0[2]*v0[2] + v0[3]*v0[3]
            + v1[0]*v1[0] + v1[1]*v1[1] + v1[2]*v1[2] + v1[3]*v1[3];
        bf16x8 hv;
        #pragma unroll
        for (int j = 0; j < 4; ++j) { hv[j] = (short)f32_bf16(v0[j]); hv[4+j] = (short)f32_bf16(v1[j]); }
        if (valid) *(bf16x8*)(dst + (s << 10)) = hv;
    }
    ss += __shfl_xor(ss, 16); ss += __shfl_xor(ss, 32);
    if (valid && lk == 0) winv[c] = 1.0f / fmaxf(sqrtf(ss), EPSN);
}

// ---------------- gemmB: pure frag-load + MFMA + fused margin ----------------
// block = 8 waves (wm 0..3, wn 0..1); wave = 128M x 32N; block = 512M x 64N.
__global__ __launch_bounds__(512) void gemmB_kernel(const unsigned short* __restrict__ in_p,
                                                    const unsigned short* __restrict__ wp,
                                                    const float* __restrict__ winv,
                                                    const float* __restrict__ gt,
                                                    const int* __restrict__ label,
                                                    float* __restrict__ out) {
    int t = threadIdx.x, wid = t >> 6, lane = t & 63;
    int wm = wid >> 1, wn = wid & 1;
    int l15 = lane & 15, lk = lane >> 4;
    int blk = blockIdx.x;

    const char* ap = (const char*)in_p + ((wm * 8) << 14) + (lane << 4);
    int cg0 = blk * 4 + wn * 2;
    int cg0c = cg0 > CG - 2 ? CG - 2 : cg0;          // clamp so cg0c+1 valid
    const char* bp = (const char*)wp + ((size_t)cg0c << 14) + (lane << 4);

    f32x4 acc[8][2];
    #pragma unroll
    for (int m = 0; m < 8; ++m)
        #pragma unroll
        for (int n = 0; n < 2; ++n) acc[m][n] = (f32x4){0.f, 0.f, 0.f, 0.f};

    bf16x8 ar[2][8], br[4][2];
    #pragma unroll
    for (int s = 0; s < 2; ++s)
        #pragma unroll
        for (int m = 0; m < 8; ++m)
            ar[s][m] = *(const bf16x8*)(ap + (m << 14) + (s << 10));
    #pragma unroll
    for (int s = 0; s < 4; ++s)
        #pragma unroll
        for (int n = 0; n < 2; ++n)
            br[s][n] = *(const bf16x8*)(bp + (n << 14) + (s << 10));

    #pragma unroll
    for (int s = 0; s < 16; ++s) {
        #pragma unroll
        for (int m = 0; m < 8; ++m)
            #pragma unroll
            for (int n = 0; n < 2; ++n)
                acc[m][n] = __builtin_amdgcn_mfma_f32_16x16x32_bf16(ar[s & 1][m], br[s & 3][n], acc[m][n], 0, 0, 0);
        if (s + 2 < 16) {
            #pragma unroll
            for (int m = 0; m < 8; ++m)
                ar[s & 1][m] = *(const bf16x8*)(ap + (m << 14) + ((s + 2) << 10));
        }
        if (s + 4 < 16) {
            #pragma unroll
            for (int n = 0; n < 2; ++n)
                br[s & 3][n] = *(const bf16x8*)(bp + (n << 14) + ((s + 4) << 10));
        }
    }

    float invc[2];
    #pragma unroll
    for (int n = 0; n < 2; ++n) {
        int c = blk * 64 + wn * 32 + n * 16 + l15;
        invc[n] = winv[c < Cn ? c : Cn - 1];
    }

    #pragma unroll
    for (int m = 0; m < 8; ++m) {
        #pragma unroll
        for (int r = 0; r < 4; ++r) {
            int b_row = wm * 128 + m * 16 + lk * 4 + r;
            float thr = gt[b_row] - MARGIN;
            int lab   = label[b_row];
            float gv  = thr * S_SCALE;
            size_t obase = (size_t)b_row * Cn;
            #pragma unroll
            for (int n = 0; n < 2; ++n) {
                int c = blk * 64 + wn * 32 + n * 16 + l15;
                if (c < Cn) {
                    float cosv = acc[m][n][r] * invc[n];
                    cosv = fminf(fmaxf(cosv, -1.0f), 1.0f);
                    float o = (cosv > thr) ? ((T_BOOST + 1.0f) * cosv + T_BOOST) : cosv;
                    o *= S_SCALE;
                    if (c == lab) o = gv;
                    out[obase + c] = o;
                }
            }
        }
    }
}

// ---------------- fallback (r6, known-pass): fused per-step staged GEMM ----------------
constexpr int BMf = 256, BNf = 128, BKf = 32;
constexpr int PADf = 40;

__global__ __launch_bounds__(512) void gemm_fb_kernel(const unsigned short* __restrict__ in_p,
                                                      const float* __restrict__ w,
                                                      const float* __restrict__ gt,
                                                      const int* __restrict__ label,
                                                      float* __restrict__ out) {
    __shared__ unsigned short Bs[2][BNf * PADf];
    __shared__ float inv_s[BNf];

    int t = threadIdx.x, wid = t >> 6, lane = t & 63;
    int wm = wid >> 1, wn = wid & 1;
    int l15 = lane & 15, lk = lane >> 4;
    int bm = blockIdx.x, bn = blockIdx.y;

    int srow = t >> 2, q = t & 3;
    int rg = bn * BNf + srow; if (rg >= Cn) rg = Cn - 1;
    const float* wsrc = w + (size_t)rg * Dn + q * 8;
    char* sdst0 = (char*)&Bs[0][0] + srow * (PADf * 2) + q * 16;
    char* sdst1 = (char*)&Bs[1][0] + srow * (PADf * 2) + q * 16;

    const char* apb = (const char*)in_p + (((bm * 16 + wm * 4)) << 14) + (lane << 4);

    float ss = 0.f;
    f32x4 acc[4][4];
    #pragma unroll
    for (int m = 0; m < 4; ++m)
        #pragma unroll
        for (int n = 0; n < 4; ++n) acc[m][n] = (f32x4){0.f, 0.f, 0.f, 0.f};

    {
        f32x4 b0 = *(const f32x4*)(wsrc);
        f32x4 b1 = *(const f32x4*)(wsrc + 4);
        ss += b0[0]*b0[0] + b0[1]*b0[1] + b0[2]*b0[2] + b0[3]*b0[3]
            + b1[0]*b1[0] + b1[1]*b1[1] + b1[2]*b1[2] + b1[3]*b1[3];
        bf16x8 hv;
        #pragma unroll
        for (int j = 0; j < 4; ++j) { hv[j] = (short)f32_bf16(b0[j]); hv[4+j] = (short)f32_bf16(b1[j]); }
        *(bf16x8*)sdst0 = hv;
    }
    bf16x8 arf[2][4];
    #pragma unroll
    for (int s = 0; s < 2; ++s)
        #pragma unroll
        for (int m = 0; m < 4; ++m)
            arf[s][m] = *(const bf16x8*)(apb + (m << 14) + (s << 10));
    __syncthreads();

    #pragma unroll
    for (int kt = 0; kt < 16; ++kt) {
        f32x4 b0, b1;
        if (kt < 15) {
            b0 = *(const f32x4*)(wsrc + (kt + 1) * BKf);
            b1 = *(const f32x4*)(wsrc + (kt + 1) * BKf + 4);
        }
        const char* bsb = (const char*)&Bs[kt & 1][0];
        bf16x8 bfrag[4];
        #pragma unroll
        for (int nf = 0; nf < 4; ++nf) {
            int br = wn * 64 + nf * 16 + l15;
            bfrag[nf] = *(const bf16x8*)(bsb + br * (PADf * 2) + lk * 16);
        }
        #pragma unroll
        for (int m = 0; m < 4; ++m)
            #pragma unroll
            for (int nf = 0; nf < 4; ++nf)
                acc[m][nf] = __builtin_amdgcn_mfma_f32_16x16x32_bf16(arf[kt & 1][m], bfrag[nf], acc[m][nf], 0, 0, 0);
        if (kt + 2 < 16) {
            #pragma unroll
            for (int m = 0; m < 4; ++m)
                arf[kt & 1][m] = *(const bf16x8*)(apb + (m << 14) + ((kt + 2) << 10));
        }
        if (kt < 15) {
            ss += b0[0]*b0[0] + b0[1]*b0[1] + b0[2]*b0[2] + b0[3]*b0[3]
                + b1[0]*b1[0] + b1[1]*b1[1] + b1[2]*b1[2] + b1[3]*b1[3];
            bf16x8 hv;
            #pragma unroll
            for (int j = 0; j < 4; ++j) { hv[j] = (short)f32_bf16(b0[j]); hv[4+j] = (short)f32_bf16(b1[j]); }
            *(bf16x8*)(((kt & 1) ? sdst0 : sdst1)) = hv;
        }
        __syncthreads();
    }

    ss += __shfl_xor(ss, 1); ss += __shfl_xor(ss, 2);
    if (q == 0) inv_s[srow] = 1.0f / fmaxf(sqrtf(ss), EPSN);
    __syncthreads();

    float invc[4];
    #pragma unroll
    for (int nf = 0; nf < 4; ++nf) invc[nf] = inv_s[wn * 64 + nf * 16 + l15];

    #pragma unroll
    for (int m = 0; m < 4; ++m) {
        #pragma unroll
        for (int r = 0; r < 4; ++r) {
            int b_row = bm * BMf + wm * 64 + m * 16 + lk * 4 + r;
            float thr = gt[b_row] - MARGIN;
            int lab   = label[b_row];
            float gv  = thr * S_SCALE;
            size_t obase = (size_t)b_row * Cn;
            #pragma unroll
            for (int nf = 0; nf < 4; ++nf) {
                int c = bn * BNf + wn * 64 + nf * 16 + l15;
                if (c < Cn) {
                    float cosv = acc[m][nf][r] * invc[nf];
                    cosv = fminf(fmaxf(cosv, -1.0f), 1.0f);
                    float o = (cosv > thr) ? ((T_BOOST + 1.0f) * cosv + T_BOOST) : cosv;
                    o *= S_SCALE;
                    if (c == lab) o = gv;
                    out[obase + c] = o;
                }
            }
        }
    }
}

extern "C" void kernel_launch(void* const* d_in, const int* in_sizes, int n_in,
                              void* d_out, int out_size, void* d_ws, size_t ws_size,
                              hipStream_t stream) {
    const float* in  = (const float*)d_in[0];
    const float* w   = (const float*)d_in[1];
    const int* label = (const int*)d_in[2];
    float* out = (float*)d_out;

    char* ws = (char*)d_ws;
    float* gt            = (float*)ws;                     // 512 f32
    unsigned short* in_p = (unsigned short*)(ws + 4096);   // 512 KB packed A
    float* winv          = (float*)(ws + 4096 + 524288);   // 400 KB
    unsigned short* wp   = (unsigned short*)(ws + 4096 + 524288 + 400384); // 100 MB packed B
    const size_t NEED = 4096ull + 524288 + 400384 + (size_t)CG * 16384;    // ~103.3 MB

    if (ws_size >= NEED) {
        wpack_kernel<<<dim3((CG + 3) / 4), dim3(256), 0, stream>>>(w, winv, wp);
        prep_kernel<<<dim3(Bn), dim3(256), 0, stream>>>(in, w, label, gt, in_p);
        int nblk = (Cn + 63) / 64;   // 1563
        gemmB_kernel<<<dim3(nblk), dim3(512), 0, stream>>>(in_p, wp, winv, gt, label, out);
    } else {
        prep_kernel<<<dim3(Bn), dim3(256), 0, stream>>>(in, w, label, gt, in_p);
        dim3 grid(2, (Cn + BNf - 1) / BNf);
        gemm_fb_kernel<<<grid, dim3(512), 0, stream>>>(in_p, w, gt, label, out);
    }
}

// Round 8
// 239.195 us; speedup vs baseline: 1.4099x; 1.4099x over previous
//
#include <hip/hip_runtime.h>
#include <hip/hip_bf16.h>

// SVXSoftmax: cos = norm(input) @ norm(weight)^T ; margin transform ; *32
// B=512, D=512, C=100000.  out[512][100000] f32.
//
// r8: fused GEMM with m97-style async staging (global_load_lds, dbuf, one
// barrier per K-step). A: bf16-normalized input packed in fragment order
// (prep), staged LDS via gload_lds. B: raw f32 W staged via gload_lds with
// inverse-swizzled global source (rule #21) so the 128B-row reads are ~2-way;
// f32->bf16 cvt at fragment read; sumsq from same LDS reads (wm==0 waves);
// invnorm applied post-MFMA. BM=256 BN=128 BK=32, 8 waves, 64.5KB LDS
// -> 2 blocks/CU.

#define S_SCALE 32.0f
#define MARGIN  0.35f
#define T_BOOST 0.2f
#define EPSN    1e-12f

constexpr int Bn = 512;      // batch
constexpr int Dn = 512;      // dim
constexpr int Cn = 100000;   // classes
constexpr int BM = 256, BN = 128;

typedef __attribute__((ext_vector_type(8))) short bf16x8;
typedef __attribute__((ext_vector_type(4))) float f32x4;

static __device__ inline unsigned short f32_bf16(float f) {
    unsigned int u = __float_as_uint(f);
    u += 0x7FFFu + ((u >> 16) & 1u);     // round-to-nearest-even
    return (unsigned short)(u >> 16);
}

typedef __attribute__((address_space(1))) const unsigned int GUI;
typedef __attribute__((address_space(3))) unsigned int LUI;
static __device__ __forceinline__ void gl16(const void* g, void* l) {
    __builtin_amdgcn_global_load_lds((GUI*)g, (LUI*)l, 16, 0, 0);
}

// packed A layout: byte = (g<<14) + (s<<10) + (lane<<4) + j*2
//   g = row>>4, s = k>>5, lane = ((k>>3)&3)*16 + (row&15)
__global__ __launch_bounds__(256) void prep_kernel(const float* __restrict__ in,
                                                   const float* __restrict__ w,
                                                   const int* __restrict__ label,
                                                   float* __restrict__ gt,
                                                   unsigned short* __restrict__ in_p) {
    int b = blockIdx.x, t = threadIdx.x;
    const float* irow = in + (size_t)b * Dn;
    int lab = label[b];
    const float* wrow = w + (size_t)lab * Dn;
    int c = 2 * t;
    float xa = irow[c], xb = irow[c + 1];
    float ya = wrow[c], yb = wrow[c + 1];
    float s_ii = xa*xa + xb*xb, s_ww = ya*ya + yb*yb, s_iw = xa*ya + xb*yb;
    #pragma unroll
    for (int off = 32; off; off >>= 1) {
        s_ii += __shfl_xor(s_ii, off);
        s_ww += __shfl_xor(s_ww, off);
        s_iw += __shfl_xor(s_iw, off);
    }
    __shared__ float r0[4], r1[4], r2[4], bc[1];
    int wid = t >> 6;
    if ((t & 63) == 0) { r0[wid] = s_ii; r1[wid] = s_ww; r2[wid] = s_iw; }
    __syncthreads();
    if (t == 0) {
        float a  = r0[0] + r0[1] + r0[2] + r0[3];
        float cc = r1[0] + r1[1] + r1[2] + r1[3];
        float d  = r2[0] + r2[1] + r2[2] + r2[3];
        float inv_i = 1.0f / fmaxf(sqrtf(a), EPSN);
        float g = d * inv_i / fmaxf(sqrtf(cc), EPSN);
        gt[b] = fminf(fmaxf(g, -1.0f), 1.0f);
        bc[0] = inv_i;
    }
    __syncthreads();
    float inv_i = bc[0];
    int g = b >> 4, l15 = b & 15;
    int s = t >> 4, lk = (t >> 2) & 3, j2 = (t & 3) * 4;
    int lane = lk * 16 + l15;
    unsigned int off = (unsigned)((g << 14) + (s << 10) + (lane << 4)) + j2;
    unsigned int h0 = f32_bf16(xa * inv_i), h1 = f32_bf16(xb * inv_i);
    *(unsigned int*)((char*)in_p + off) = h0 | (h1 << 16);
}

// ---------------- fused async-staged GEMM + margin ----------------
__global__ __launch_bounds__(512) void gemm_kernel(const unsigned short* __restrict__ in_p,
                                                   const float* __restrict__ w,
                                                   const float* __restrict__ gt,
                                                   const int* __restrict__ label,
                                                   float* __restrict__ out) {
    __shared__ __align__(16) char Ab[2][16384];   // bf16 A tile, fragment-packed
    __shared__ __align__(16) char Bb[2][16384];   // f32 B tile, rows 128B, pieces swizzled
    __shared__ float inv_s[BN];

    int t = threadIdx.x, wid = t >> 6, lane = t & 63;
    int wm = wid >> 1, wn = wid & 1;             // wave = 64M x 64N
    int l15 = lane & 15, lk = lane >> 4;
    int bm = blockIdx.x, bn = blockIdx.y;

    // ---- staging addresses (this thread's share: 2 A-chunks + 2 B-chunks) ----
    const char* asrc = (const char*)in_p + ((size_t)(bm * 16) << 14) + (lane << 4);
    int g0 = wid * 2, g1 = wid * 2 + 1;          // A chunk = m-group (1KB)
    int c0 = wid * 2, c1 = wid * 2 + 1;          // B chunk = 8 rows (1KB)
    int rmod = lane >> 3;                         // row-in-chunk = row&7
    int psrc = (lane & 7) ^ rmod;                 // inverse-swizzled source piece
    int r0g = bn * BN + 8 * c0 + rmod; if (r0g >= Cn) r0g = Cn - 1;
    int r1g = bn * BN + 8 * c1 + rmod; if (r1g >= Cn) r1g = Cn - 1;
    const char* bsrc0 = (const char*)w + (size_t)r0g * 2048 + psrc * 16;
    const char* bsrc1 = (const char*)w + (size_t)r1g * 2048 + psrc * 16;

    #define STAGE(kt, buf)                                                        \
        do {                                                                      \
            gl16(asrc + ((size_t)g0 << 14) + ((kt) << 10), &Ab[buf][g0*1024 + lane*16]); \
            gl16(asrc + ((size_t)g1 << 14) + ((kt) << 10), &Ab[buf][g1*1024 + lane*16]); \
            gl16(bsrc0 + (kt) * 128, &Bb[buf][c0*1024 + lane*16]);                \
            gl16(bsrc1 + (kt) * 128, &Bb[buf][c1*1024 + lane*16]);                \
        } while (0)

    f32x4 acc[4][4];
    #pragma unroll
    for (int m = 0; m < 4; ++m)
        #pragma unroll
        for (int n = 0; n < 4; ++n) acc[m][n] = (f32x4){0.f, 0.f, 0.f, 0.f};
    float ssq[4] = {0.f, 0.f, 0.f, 0.f};

    STAGE(0, 0);
    __syncthreads();

    #pragma unroll
    for (int kt = 0; kt < 16; ++kt) {
        int cur = kt & 1;
        if (kt < 15) STAGE(kt + 1, cur ^ 1);

        // A fragments (already bf16, packed)
        bf16x8 ar[4];
        #pragma unroll
        for (int mf = 0; mf < 4; ++mf)
            ar[mf] = *(const bf16x8*)&Ab[cur][(wm * 4 + mf) * 1024 + lane * 16];

        // B fragments: de-swizzled f32 reads + cvt (+ sumsq in wm==0 waves)
        bf16x8 bfrag[4];
        #pragma unroll
        for (int nf = 0; nf < 4; ++nf) {
            int r = wn * 64 + nf * 16 + l15;
            const char* rb = &Bb[cur][r * 128];
            int q0 = (2 * lk) ^ (r & 7), q1 = (2 * lk + 1) ^ (r & 7);
            f32x4 v0 = *(const f32x4*)(rb + q0 * 16);
            f32x4 v1 = *(const f32x4*)(rb + q1 * 16);
            bf16x8 hv;
            #pragma unroll
            for (int j = 0; j < 4; ++j) {
                hv[j]     = (short)f32_bf16(v0[j]);
                hv[4 + j] = (short)f32_bf16(v1[j]);
            }
            bfrag[nf] = hv;
            if (wm == 0)
                ssq[nf] += v0[0]*v0[0] + v0[1]*v0[1] + v0[2]*v0[2] + v0[3]*v0[3]
                         + v1[0]*v1[0] + v1[1]*v1[1] + v1[2]*v1[2] + v1[3]*v1[3];
        }

        #pragma unroll
        for (int mf = 0; mf < 4; ++mf)
            #pragma unroll
            for (int nf = 0; nf < 4; ++nf)
                acc[mf][nf] = __builtin_amdgcn_mfma_f32_16x16x32_bf16(ar[mf], bfrag[nf], acc[mf][nf], 0, 0, 0);

        __syncthreads();
    }

    // ---- invnorm from accumulated sumsq (wm==0 waves own all 128 rows) ----
    if (wm == 0) {
        #pragma unroll
        for (int nf = 0; nf < 4; ++nf) {
            float s = ssq[nf];
            s += __shfl_xor(s, 16); s += __shfl_xor(s, 32);   // reduce over lk
            if (lk == 0) inv_s[wn * 64 + nf * 16 + l15] = 1.0f / fmaxf(sqrtf(s), EPSN);
        }
    }
    __syncthreads();

    float invc[4];
    #pragma unroll
    for (int nf = 0; nf < 4; ++nf) invc[nf] = inv_s[wn * 64 + nf * 16 + l15];

    // ---- epilogue: invnorm, clamp, margin, label scatter, scale ----
    #pragma unroll
    for (int mf = 0; mf < 4; ++mf) {
        #pragma unroll
        for (int r = 0; r < 4; ++r) {
            int b_row = bm * BM + wm * 64 + mf * 16 + lk * 4 + r;
            float thr = gt[b_row] - MARGIN;
            int lab   = label[b_row];
            float gv  = thr * S_SCALE;
            size_t obase = (size_t)b_row * Cn;
            #pragma unroll
            for (int nf = 0; nf < 4; ++nf) {
                int c = bn * BN + wn * 64 + nf * 16 + l15;
                if (c < Cn) {
                    float cosv = acc[mf][nf][r] * invc[nf];
                    cosv = fminf(fmaxf(cosv, -1.0f), 1.0f);
                    float o = (cosv > thr) ? ((T_BOOST + 1.0f) * cosv + T_BOOST) : cosv;
                    o *= S_SCALE;
                    if (c == lab) o = gv;
                    out[obase + c] = o;
                }
            }
        }
    }
}

extern "C" void kernel_launch(void* const* d_in, const int* in_sizes, int n_in,
                              void* d_out, int out_size, void* d_ws, size_t ws_size,
                              hipStream_t stream) {
    const float* in  = (const float*)d_in[0];
    const float* w   = (const float*)d_in[1];
    const int* label = (const int*)d_in[2];
    float* out = (float*)d_out;

    char* ws = (char*)d_ws;
    float* gt            = (float*)ws;                   // 512 f32
    unsigned short* in_p = (unsigned short*)(ws + 4096); // packed 512KB

    prep_kernel<<<dim3(Bn), dim3(256), 0, stream>>>(in, w, label, gt, in_p);
    dim3 grid(2, (Cn + BN - 1) / BN);   // M fast -> M-pair shares W via L3
    gemm_kernel<<<grid, dim3(512), 0, stream>>>(in_p, w, gt, label, out);
}

// Round 9
// 196.181 us; speedup vs baseline: 1.7191x; 1.2193x over previous
//
#include <hip/hip_runtime.h>
#include <hip/hip_bf16.h>

// SVXSoftmax: cos = norm(input) @ norm(weight)^T ; margin transform ; *32
// B=512, D=512, C=100000.  out[512][100000] f32.
//
// r9: split + lean high-occupancy GEMM.
//  - prep: gt + bf16-normalized input packed in MFMA fragment order (512KB, L2).
//  - wpack: stream W f32 -> raw bf16 fragment-packed (98MiB ws, L3-resident)
//    + per-row invnorm (applied post-MFMA; proven numerics, absmax 0.0625).
//  - gemm2: NO conversion in-loop. 256 thr / 4 waves, tile 128x128, BK=32.
//    Staging = pure linear global_load_lds(16B) of packed bf16 (A 8KB + B 8KB
//    per step, dbuf, ONE barrier/step). Fragments = conflict-free 1KB
//    lane-contiguous ds_read_b128. 32.5KB LDS, ~111 VGPR, launch_bounds(256,4)
//    => 4 blocks/CU (16 waves) of phase-staggered independent blocks — the
//    r1-proven TLP mechanism, with zero VALU fat.
//  - fallback to r6 fused kernel if ws too small.

#define S_SCALE 32.0f
#define MARGIN  0.35f
#define T_BOOST 0.2f
#define EPSN    1e-12f

constexpr int Bn = 512;      // batch
constexpr int Dn = 512;      // dim
constexpr int Cn = 100000;   // classes
constexpr int CG = Cn / 16;  // 6250 class groups of 16

typedef __attribute__((ext_vector_type(8))) short bf16x8;
typedef __attribute__((ext_vector_type(4))) float f32x4;

static __device__ inline unsigned short f32_bf16(float f) {
    unsigned int u = __float_as_uint(f);
    u += 0x7FFFu + ((u >> 16) & 1u);     // round-to-nearest-even
    return (unsigned short)(u >> 16);
}

typedef __attribute__((address_space(1))) const unsigned int GUI;
typedef __attribute__((address_space(3))) unsigned int LUI;
static __device__ __forceinline__ void gl16(const void* g, void* l) {
    __builtin_amdgcn_global_load_lds((GUI*)g, (LUI*)l, 16, 0, 0);
}

// fragment packing: byte = (g<<14) + (s<<10) + (lane<<4) + (k&7)*2
//   g = row>>4, s = k>>5, lane = ((k>>3)&3)*16 + (row&15)
__global__ __launch_bounds__(256) void prep_kernel(const float* __restrict__ in,
                                                   const float* __restrict__ w,
                                                   const int* __restrict__ label,
                                                   float* __restrict__ gt,
                                                   unsigned short* __restrict__ in_p) {
    int b = blockIdx.x, t = threadIdx.x;
    const float* irow = in + (size_t)b * Dn;
    int lab = label[b];
    const float* wrow = w + (size_t)lab * Dn;
    int c = 2 * t;
    float xa = irow[c], xb = irow[c + 1];
    float ya = wrow[c], yb = wrow[c + 1];
    float s_ii = xa*xa + xb*xb, s_ww = ya*ya + yb*yb, s_iw = xa*ya + xb*yb;
    #pragma unroll
    for (int off = 32; off; off >>= 1) {
        s_ii += __shfl_xor(s_ii, off);
        s_ww += __shfl_xor(s_ww, off);
        s_iw += __shfl_xor(s_iw, off);
    }
    __shared__ float r0[4], r1[4], r2[4], bc[1];
    int wid = t >> 6;
    if ((t & 63) == 0) { r0[wid] = s_ii; r1[wid] = s_ww; r2[wid] = s_iw; }
    __syncthreads();
    if (t == 0) {
        float a  = r0[0] + r0[1] + r0[2] + r0[3];
        float cc = r1[0] + r1[1] + r1[2] + r1[3];
        float d  = r2[0] + r2[1] + r2[2] + r2[3];
        float inv_i = 1.0f / fmaxf(sqrtf(a), EPSN);
        float g = d * inv_i / fmaxf(sqrtf(cc), EPSN);
        gt[b] = fminf(fmaxf(g, -1.0f), 1.0f);
        bc[0] = inv_i;
    }
    __syncthreads();
    float inv_i = bc[0];
    int g = b >> 4, l15 = b & 15;
    int s = t >> 4, lk = (t >> 2) & 3, j2 = (t & 3) * 4;
    int lane = lk * 16 + l15;
    unsigned int off = (unsigned)((g << 14) + (s << 10) + (lane << 4)) + j2;
    unsigned int h0 = f32_bf16(xa * inv_i), h1 = f32_bf16(xb * inv_i);
    *(unsigned int*)((char*)in_p + off) = h0 | (h1 << 16);
}

// ---------------- wpack: W f32 -> raw bf16 fragment-packed + invnorm ----------------
__global__ __launch_bounds__(256) void wpack_kernel(const float* __restrict__ w,
                                                    float* __restrict__ winv,
                                                    unsigned short* __restrict__ wp) {
    int wave = blockIdx.x * 4 + (threadIdx.x >> 6);
    int lane = threadIdx.x & 63;
    bool valid = wave < CG;
    int cg = valid ? wave : CG - 1;
    int c  = cg * 16 + (lane & 15);
    int lk = lane >> 4;
    const float* src = w + (size_t)c * Dn + lk * 8;
    char* dst = (char*)wp + ((size_t)cg << 14) + (lane << 4);
    float ss = 0.f;
    #pragma unroll
    for (int s = 0; s < 16; ++s) {
        f32x4 v0 = *(const f32x4*)(src + s * 32);
        f32x4 v1 = *(const f32x4*)(src + s * 32 + 4);
        ss += v0[0]*v0[0] + v0[1]*v0[1] + v0[2]*v0[2] + v0[3]*v0[3]
            + v1[0]*v1[0] + v1[1]*v1[1] + v1[2]*v1[2] + v1[3]*v1[3];
        bf16x8 hv;
        #pragma unroll
        for (int j = 0; j < 4; ++j) { hv[j] = (short)f32_bf16(v0[j]); hv[4+j] = (short)f32_bf16(v1[j]); }
        if (valid) *(bf16x8*)(dst + (s << 10)) = hv;
    }
    ss += __shfl_xor(ss, 16); ss += __shfl_xor(ss, 32);
    if (valid && lk == 0) winv[c] = 1.0f / fmaxf(sqrtf(ss), EPSN);
}

// ---------------- gemm2: lean LDS-staged bf16 GEMM + fused margin ----------------
// 256 thr / 4 waves (2wm x 2wn); block tile 128M x 128N; wave 64x64.
__global__ __launch_bounds__(256, 4) void gemm2_kernel(const unsigned short* __restrict__ in_p,
                                                       const unsigned short* __restrict__ wp,
                                                       const float* __restrict__ winv,
                                                       const float* __restrict__ gt,
                                                       const int* __restrict__ label,
                                                       float* __restrict__ out) {
    __shared__ __align__(16) char Ab[2][8192];
    __shared__ __align__(16) char Bb[2][8192];

    int t = threadIdx.x, wv = t >> 6, lane = t & 63;
    int wm = wv >> 1, wn = wv & 1;
    int l15 = lane & 15, lk = lane >> 4;
    int bm = blockIdx.x, bn = blockIdx.y;

    // staging: wave wv stages A chunks {wv*2, wv*2+1} and B chunks {wv*2, wv*2+1}
    int ac0 = wv * 2, ac1 = wv * 2 + 1;          // A local group 0..7
    const char* asrc0 = (const char*)in_p + ((size_t)(bm * 8 + ac0) << 14) + (lane << 4);
    const char* asrc1 = (const char*)in_p + ((size_t)(bm * 8 + ac1) << 14) + (lane << 4);
    int bg0 = bn * 8 + ac0; if (bg0 >= CG) bg0 = CG - 1;
    int bg1 = bn * 8 + ac1; if (bg1 >= CG) bg1 = CG - 1;
    const char* bsrc0 = (const char*)wp + ((size_t)bg0 << 14) + (lane << 4);
    const char* bsrc1 = (const char*)wp + ((size_t)bg1 << 14) + (lane << 4);

    #define STAGE2(kt, buf)                                              \
        do {                                                             \
            gl16(asrc0 + ((kt) << 10), &Ab[buf][ac0*1024 + lane*16]);    \
            gl16(asrc1 + ((kt) << 10), &Ab[buf][ac1*1024 + lane*16]);    \
            gl16(bsrc0 + ((kt) << 10), &Bb[buf][ac0*1024 + lane*16]);    \
            gl16(bsrc1 + ((kt) << 10), &Bb[buf][ac1*1024 + lane*16]);    \
        } while (0)

    f32x4 acc[4][4];
    #pragma unroll
    for (int m = 0; m < 4; ++m)
        #pragma unroll
        for (int n = 0; n < 4; ++n) acc[m][n] = (f32x4){0.f, 0.f, 0.f, 0.f};

    STAGE2(0, 0);
    __syncthreads();

    #pragma unroll 2
    for (int kt = 0; kt < 16; ++kt) {
        int cur = kt & 1;
        if (kt < 15) STAGE2(kt + 1, cur ^ 1);

        bf16x8 ar[4], br[4];
        #pragma unroll
        for (int mf = 0; mf < 4; ++mf)
            ar[mf] = *(const bf16x8*)&Ab[cur][(wm * 4 + mf) * 1024 + lane * 16];
        #pragma unroll
        for (int nf = 0; nf < 4; ++nf)
            br[nf] = *(const bf16x8*)&Bb[cur][(wn * 4 + nf) * 1024 + lane * 16];

        #pragma unroll
        for (int mf = 0; mf < 4; ++mf)
            #pragma unroll
            for (int nf = 0; nf < 4; ++nf)
                acc[mf][nf] = __builtin_amdgcn_mfma_f32_16x16x32_bf16(ar[mf], br[nf], acc[mf][nf], 0, 0, 0);

        __syncthreads();
    }

    float invc[4];
    #pragma unroll
    for (int nf = 0; nf < 4; ++nf) {
        int c = bn * 128 + wn * 64 + nf * 16 + l15;
        invc[nf] = winv[c < Cn ? c : Cn - 1];
    }

    #pragma unroll
    for (int mf = 0; mf < 4; ++mf) {
        #pragma unroll
        for (int r = 0; r < 4; ++r) {
            int b_row = bm * 128 + wm * 64 + mf * 16 + lk * 4 + r;
            float thr = gt[b_row] - MARGIN;
            int lab   = label[b_row];
            float gv  = thr * S_SCALE;
            size_t obase = (size_t)b_row * Cn;
            #pragma unroll
            for (int nf = 0; nf < 4; ++nf) {
                int c = bn * 128 + wn * 64 + nf * 16 + l15;
                if (c < Cn) {
                    float cosv = acc[mf][nf][r] * invc[nf];
                    cosv = fminf(fmaxf(cosv, -1.0f), 1.0f);
                    float o = (cosv > thr) ? ((T_BOOST + 1.0f) * cosv + T_BOOST) : cosv;
                    o *= S_SCALE;
                    if (c == lab) o = gv;
                    out[obase + c] = o;
                }
            }
        }
    }
}

// ---------------- fallback (r6, known-pass): fused per-step staged GEMM ----------------
constexpr int BMf = 256, BNf = 128, BKf = 32;
constexpr int PADf = 40;

__global__ __launch_bounds__(512) void gemm_fb_kernel(const unsigned short* __restrict__ in_p,
                                                      const float* __restrict__ w,
                                                      const float* __restrict__ gt,
                                                      const int* __restrict__ label,
                                                      float* __restrict__ out) {
    __shared__ unsigned short Bs[2][BNf * PADf];
    __shared__ float inv_s[BNf];

    int t = threadIdx.x, wid = t >> 6, lane = t & 63;
    int wm = wid >> 1, wn = wid & 1;
    int l15 = lane & 15, lk = lane >> 4;
    int bm = blockIdx.x, bn = blockIdx.y;

    int srow = t >> 2, q = t & 3;
    int rg = bn * BNf + srow; if (rg >= Cn) rg = Cn - 1;
    const float* wsrc = w + (size_t)rg * Dn + q * 8;
    char* sdst0 = (char*)&Bs[0][0] + srow * (PADf * 2) + q * 16;
    char* sdst1 = (char*)&Bs[1][0] + srow * (PADf * 2) + q * 16;

    const char* apb = (const char*)in_p + (((bm * 16 + wm * 4)) << 14) + (lane << 4);

    float ss = 0.f;
    f32x4 acc[4][4];
    #pragma unroll
    for (int m = 0; m < 4; ++m)
        #pragma unroll
        for (int n = 0; n < 4; ++n) acc[m][n] = (f32x4){0.f, 0.f, 0.f, 0.f};

    {
        f32x4 b0 = *(const f32x4*)(wsrc);
        f32x4 b1 = *(const f32x4*)(wsrc + 4);
        ss += b0[0]*b0[0] + b0[1]*b0[1] + b0[2]*b0[2] + b0[3]*b0[3]
            + b1[0]*b1[0] + b1[1]*b1[1] + b1[2]*b1[2] + b1[3]*b1[3];
        bf16x8 hv;
        #pragma unroll
        for (int j = 0; j < 4; ++j) { hv[j] = (short)f32_bf16(b0[j]); hv[4+j] = (short)f32_bf16(b1[j]); }
        *(bf16x8*)sdst0 = hv;
    }
    bf16x8 arf[2][4];
    #pragma unroll
    for (int s = 0; s < 2; ++s)
        #pragma unroll
        for (int m = 0; m < 4; ++m)
            arf[s][m] = *(const bf16x8*)(apb + (m << 14) + (s << 10));
    __syncthreads();

    #pragma unroll
    for (int kt = 0; kt < 16; ++kt) {
        f32x4 b0, b1;
        if (kt < 15) {
            b0 = *(const f32x4*)(wsrc + (kt + 1) * BKf);
            b1 = *(const f32x4*)(wsrc + (kt + 1) * BKf + 4);
        }
        const char* bsb = (const char*)&Bs[kt & 1][0];
        bf16x8 bfrag[4];
        #pragma unroll
        for (int nf = 0; nf < 4; ++nf) {
            int br = wn * 64 + nf * 16 + l15;
            bfrag[nf] = *(const bf16x8*)(bsb + br * (PADf * 2) + lk * 16);
        }
        #pragma unroll
        for (int m = 0; m < 4; ++m)
            #pragma unroll
            for (int nf = 0; nf < 4; ++nf)
                acc[m][nf] = __builtin_amdgcn_mfma_f32_16x16x32_bf16(arf[kt & 1][m], bfrag[nf], acc[m][nf], 0, 0, 0);
        if (kt + 2 < 16) {
            #pragma unroll
            for (int m = 0; m < 4; ++m)
                arf[kt & 1][m] = *(const bf16x8*)(apb + (m << 14) + ((kt + 2) << 10));
        }
        if (kt < 15) {
            ss += b0[0]*b0[0] + b0[1]*b0[1] + b0[2]*b0[2] + b0[3]*b0[3]
                + b1[0]*b1[0] + b1[1]*b1[1] + b1[2]*b1[2] + b1[3]*b1[3];
            bf16x8 hv;
            #pragma unroll
            for (int j = 0; j < 4; ++j) { hv[j] = (short)f32_bf16(b0[j]); hv[4+j] = (short)f32_bf16(b1[j]); }
            *(bf16x8*)(((kt & 1) ? sdst0 : sdst1)) = hv;
        }
        __syncthreads();
    }

    ss += __shfl_xor(ss, 1); ss += __shfl_xor(ss, 2);
    if (q == 0) inv_s[srow] = 1.0f / fmaxf(sqrtf(ss), EPSN);
    __syncthreads();

    float invc[4];
    #pragma unroll
    for (int nf = 0; nf < 4; ++nf) invc[nf] = inv_s[wn * 64 + nf * 16 + l15];

    #pragma unroll
    for (int m = 0; m < 4; ++m) {
        #pragma unroll
        for (int r = 0; r < 4; ++r) {
            int b_row = bm * BMf + wm * 64 + m * 16 + lk * 4 + r;
            float thr = gt[b_row] - MARGIN;
            int lab   = label[b_row];
            float gv  = thr * S_SCALE;
            size_t obase = (size_t)b_row * Cn;
            #pragma unroll
            for (int nf = 0; nf < 4; ++nf) {
                int c = bn * BNf + wn * 64 + nf * 16 + l15;
                if (c < Cn) {
                    float cosv = acc[m][nf][r] * invc[nf];
                    cosv = fminf(fmaxf(cosv, -1.0f), 1.0f);
                    float o = (cosv > thr) ? ((T_BOOST + 1.0f) * cosv + T_BOOST) : cosv;
                    o *= S_SCALE;
                    if (c == lab) o = gv;
                    out[obase + c] = o;
                }
            }
        }
    }
}

extern "C" void kernel_launch(void* const* d_in, const int* in_sizes, int n_in,
                              void* d_out, int out_size, void* d_ws, size_t ws_size,
                              hipStream_t stream) {
    const float* in  = (const float*)d_in[0];
    const float* w   = (const float*)d_in[1];
    const int* label = (const int*)d_in[2];
    float* out = (float*)d_out;

    char* ws = (char*)d_ws;
    float* gt            = (float*)ws;                     // 512 f32
    unsigned short* in_p = (unsigned short*)(ws + 4096);   // 512 KB packed A
    float* winv          = (float*)(ws + 4096 + 524288);   // 400 KB
    unsigned short* wp   = (unsigned short*)(ws + 4096 + 524288 + 400384); // ~98 MB packed B
    const size_t NEED = 4096ull + 524288 + 400384 + (size_t)CG * 16384;

    if (ws_size >= NEED) {
        wpack_kernel<<<dim3((CG + 3) / 4), dim3(256), 0, stream>>>(w, winv, wp);
        prep_kernel<<<dim3(Bn), dim3(256), 0, stream>>>(in, w, label, gt, in_p);
        dim3 grid(4, (Cn + 127) / 128);   // bm fastest: siblings share B tile via L2/L3
        gemm2_kernel<<<grid, dim3(256), 0, stream>>>(in_p, wp, winv, gt, label, out);
    } else {
        prep_kernel<<<dim3(Bn), dim3(256), 0, stream>>>(in, w, label, gt, in_p);
        dim3 grid(2, (Cn + BNf - 1) / BNf);
        gemm_fb_kernel<<<grid, dim3(512), 0, stream>>>(in_p, w, gt, label, out);
    }
}